// Round 2
// baseline (2737.547 us; speedup 1.0000x reference)
//
#include <hip/hip_runtime.h>
#include <hip/hip_fp16.h>
#include <math.h>

#define NB 4
#define NN 4096
#define NC 128
#define RST 4100            // padded stride for r/c arrays (keeps float4 alignment)
#define MU (1.0f/8192.0f)

// ---------------- scalars ----------------
__global__ void scalars_k(const float* __restrict__ ds, const float* __restrict__ gw,
                          const float* __restrict__ ct, float* __restrict__ scal) {
    if (threadIdx.x == 0) {
        float t = ct[0];
        scal[0] = 1.0f / t;                                   // raw temp reciprocal (scores = sim/temp_raw)
        float tc = fminf(fmaxf(t, 0.03f), 10.0f);
        float d = fminf(fmaxf(ds[0] / tc, -50.0f), 50.0f);
        scal[1] = __expf(d);                                  // kd = exp(dustbin/temp_clipped)
        scal[2] = fminf(fmaxf(gw[0], 0.0f), 2.0f);            // clipped geo weight
    }
}

// ---------------- inverse norms ----------------
__global__ __launch_bounds__(256) void invnorm_k(const float* __restrict__ fA, const float* __restrict__ fB,
                                                 float* __restrict__ invA, float* __restrict__ invB) {
    int wv = blockIdx.x * 4 + (threadIdx.x >> 6);   // 0..32767
    int lane = threadIdx.x & 63;
    const float* src;
    float* dst;
    if (wv < NB * NN) { src = fA + (size_t)wv * NC; dst = invA + wv; }
    else              { src = fB + (size_t)(wv - NB * NN) * NC; dst = invB + (wv - NB * NN); }
    float2 x = *(const float2*)(src + 2 * lane);
    float ss = x.x * x.x + x.y * x.y;
#pragma unroll
    for (int off = 32; off; off >>= 1) ss += __shfl_down(ss, off);
    if (lane == 0) *dst = 1.0f / fmaxf(sqrtf(ss), 1e-12f);
}

// ---------------- fp32 GEMM: raw_sim ----------------
__global__ __launch_bounds__(256) void gemm_k(const float* __restrict__ A, const float* __restrict__ B,
                                              const float* __restrict__ invA, const float* __restrict__ invB,
                                              float* __restrict__ sim_out) {
    __shared__ float As[16][128];
    __shared__ float Bs[16][128];
    int b = blockIdx.z;
    int m0 = blockIdx.y * 128, n0 = blockIdx.x * 128;
    const float* Ab = A + (size_t)b * NN * NC;
    const float* Bb = B + (size_t)b * NN * NC;
    int t = threadIdx.x;
    int tr = t >> 2, tq = t & 3;
    int ty = t >> 4, tx = t & 15;
    float acc[8][8] = {};
    for (int k0 = 0; k0 < NC; k0 += 16) {
        float4 a0 = *(const float4*)(Ab + (size_t)(m0 + tr) * NC + k0 + 4 * tq);
        float4 a1 = *(const float4*)(Ab + (size_t)(m0 + tr + 64) * NC + k0 + 4 * tq);
        float4 b0 = *(const float4*)(Bb + (size_t)(n0 + tr) * NC + k0 + 4 * tq);
        float4 b1 = *(const float4*)(Bb + (size_t)(n0 + tr + 64) * NC + k0 + 4 * tq);
        __syncthreads();
        As[4 * tq + 0][tr] = a0.x; As[4 * tq + 1][tr] = a0.y; As[4 * tq + 2][tr] = a0.z; As[4 * tq + 3][tr] = a0.w;
        As[4 * tq + 0][tr + 64] = a1.x; As[4 * tq + 1][tr + 64] = a1.y; As[4 * tq + 2][tr + 64] = a1.z; As[4 * tq + 3][tr + 64] = a1.w;
        Bs[4 * tq + 0][tr] = b0.x; Bs[4 * tq + 1][tr] = b0.y; Bs[4 * tq + 2][tr] = b0.z; Bs[4 * tq + 3][tr] = b0.w;
        Bs[4 * tq + 0][tr + 64] = b1.x; Bs[4 * tq + 1][tr + 64] = b1.y; Bs[4 * tq + 2][tr + 64] = b1.z; Bs[4 * tq + 3][tr + 64] = b1.w;
        __syncthreads();
#pragma unroll
        for (int k = 0; k < 16; k++) {
            float av[8], bv[8];
            *(float4*)av = *(const float4*)&As[k][ty * 8];
            *(float4*)(av + 4) = *(const float4*)&As[k][ty * 8 + 4];
            *(float4*)bv = *(const float4*)&Bs[k][tx * 8];
            *(float4*)(bv + 4) = *(const float4*)&Bs[k][tx * 8 + 4];
#pragma unroll
            for (int i = 0; i < 8; i++)
#pragma unroll
                for (int j = 0; j < 8; j++) acc[i][j] = fmaf(av[i], bv[j], acc[i][j]);
        }
    }
    int m_base = m0 + ty * 8;
    int n_base = n0 + tx * 8;
    float ib[8];
#pragma unroll
    for (int j = 0; j < 8; j++) ib[j] = invB[(size_t)b * NN + n_base + j];
#pragma unroll
    for (int i = 0; i < 8; i++) {
        int m = m_base + i;
        float ia = invA[(size_t)b * NN + m];
        float row[8];
#pragma unroll
        for (int j = 0; j < 8; j++) row[j] = acc[i][j] * ia * ib[j];
        size_t rbase = ((size_t)b * NN + m) * NN + n_base;
        float4* so = (float4*)(sim_out + rbase);
        so[0] = make_float4(row[0], row[1], row[2], row[3]);
        so[1] = make_float4(row[4], row[5], row[6], row[7]);
    }
}

// ---------------- Sinkhorn init ----------------
__global__ void init_sink_k(float* __restrict__ c, float* __restrict__ sums) {
    int i = blockIdx.x * 256 + threadIdx.x;
    if (i < NB * RST) c[i] = 1.0f;
    if (i < NB) { sums[i] = 0.0f; sums[NB + i] = (float)NN; }   // sum_r=0, sum_c=N (v=0 -> c=1)
}

__device__ __forceinline__ float kval(float s, float ict) {
    float z = fminf(fmaxf(s * ict, -50.0f), 50.0f);
    return __expf(z);
}

// ---------------- Sinkhorn row pass: r = mu / (K c + kd*c_dust), K = exp(sim/t) on the fly ----------------
__global__ __launch_bounds__(256) void row_pass_k(const float* __restrict__ sim, const float* __restrict__ c,
                                                  float* __restrict__ r, float* __restrict__ sums,
                                                  const float* __restrict__ scal) {
    int b = blockIdx.y;
    int warp = threadIdx.x >> 6;
    int lane = threadIdx.x & 63;
    int wv = blockIdx.x * 4 + warp;
    const float* cb = c + (size_t)b * RST;
    float kd = scal[1];
    float ict = scal[0];
    float cr[64];
#pragma unroll
    for (int s = 0; s < 8; s++) {
        float4 u0 = *(const float4*)(cb + 512 * s + 8 * lane);
        float4 u1 = *(const float4*)(cb + 512 * s + 8 * lane + 4);
        cr[8 * s + 0] = u0.x; cr[8 * s + 1] = u0.y; cr[8 * s + 2] = u0.z; cr[8 * s + 3] = u0.w;
        cr[8 * s + 4] = u1.x; cr[8 * s + 5] = u1.y; cr[8 * s + 6] = u1.z; cr[8 * s + 7] = u1.w;
    }
    float c_dust = cb[NN];
    const float* Sb = sim + (size_t)b * NN * NN;
    float local_sum = 0.0f;
    for (int j = 0; j < 4; j++) {
        int m = wv + 1024 * j;
        const float4* Srow = (const float4*)(Sb + (size_t)m * NN);
        float acc = 0.0f;
#pragma unroll
        for (int s = 0; s < 8; s++) {
            float4 v0 = Srow[128 * s + 2 * lane];
            float4 v1 = Srow[128 * s + 2 * lane + 1];
            acc = fmaf(kval(v0.x, ict), cr[8 * s + 0], acc);
            acc = fmaf(kval(v0.y, ict), cr[8 * s + 1], acc);
            acc = fmaf(kval(v0.z, ict), cr[8 * s + 2], acc);
            acc = fmaf(kval(v0.w, ict), cr[8 * s + 3], acc);
            acc = fmaf(kval(v1.x, ict), cr[8 * s + 4], acc);
            acc = fmaf(kval(v1.y, ict), cr[8 * s + 5], acc);
            acc = fmaf(kval(v1.z, ict), cr[8 * s + 6], acc);
            acc = fmaf(kval(v1.w, ict), cr[8 * s + 7], acc);
        }
#pragma unroll
        for (int off = 32; off; off >>= 1) acc += __shfl_down(acc, off);
        if (lane == 0) {
            float rm = MU / (acc + kd * c_dust);
            r[(size_t)b * RST + m] = rm;
            local_sum += rm;
        }
    }
    if (lane == 0) atomicAdd(&sums[b], local_sum);
    if (wv == 0 && lane == 0) {
        float sc = sums[NB + b];                 // sum_c from previous col pass
        r[(size_t)b * RST + NN] = 0.5f / (kd * sc + c_dust);  // dustbin row
        sums[NB + b] = 0.0f;                     // zero for next col finalize
    }
}

// ---------------- Sinkhorn col pass (partials over row splits) ----------------
__global__ __launch_bounds__(256) void col_partial_k(const float* __restrict__ sim, const float* __restrict__ r,
                                                     float* __restrict__ partial, const float* __restrict__ scal) {
    int b = blockIdx.z, split = blockIdx.y;
    int n0 = blockIdx.x * 2048 + 8 * threadIdx.x;
    const float* rb = r + (size_t)b * RST;
    const float* Sb = sim + (size_t)b * NN * NN;
    float ict = scal[0];
    float acc[8] = {};
    int m0 = split * 64;
#pragma unroll 2
    for (int m = m0; m < m0 + 64; m++) {
        float rm = rb[m];
        float4 v0 = *(const float4*)(Sb + (size_t)m * NN + n0);
        float4 v1 = *(const float4*)(Sb + (size_t)m * NN + n0 + 4);
        acc[0] = fmaf(kval(v0.x, ict), rm, acc[0]);
        acc[1] = fmaf(kval(v0.y, ict), rm, acc[1]);
        acc[2] = fmaf(kval(v0.z, ict), rm, acc[2]);
        acc[3] = fmaf(kval(v0.w, ict), rm, acc[3]);
        acc[4] = fmaf(kval(v1.x, ict), rm, acc[4]);
        acc[5] = fmaf(kval(v1.y, ict), rm, acc[5]);
        acc[6] = fmaf(kval(v1.z, ict), rm, acc[6]);
        acc[7] = fmaf(kval(v1.w, ict), rm, acc[7]);
    }
    float* pb = partial + ((size_t)(b * 64 + split)) * NN + n0;
    ((float4*)pb)[0] = make_float4(acc[0], acc[1], acc[2], acc[3]);
    ((float4*)pb)[1] = make_float4(acc[4], acc[5], acc[6], acc[7]);
}

__global__ __launch_bounds__(256) void col_finalize_k(const float* __restrict__ partial, const float* __restrict__ r,
                                                      float* __restrict__ c, float* __restrict__ sums,
                                                      const float* __restrict__ scal) {
    int b = blockIdx.y;
    int n = blockIdx.x * 256 + threadIdx.x;
    float kd = scal[1];
    float rd = r[(size_t)b * RST + NN];
    float s = kd * rd;
#pragma unroll 8
    for (int sp = 0; sp < 64; sp++) s += partial[((size_t)(b * 64 + sp)) * NN + n];
    float cn = MU / s;
    c[(size_t)b * RST + n] = cn;
    float ls = cn;
#pragma unroll
    for (int off = 32; off; off >>= 1) ls += __shfl_down(ls, off);
    if ((threadIdx.x & 63) == 0) atomicAdd(&sums[NB + b], ls);
    if (threadIdx.x == 0 && blockIdx.x == 0) {
        float sr = sums[b];                       // sum_r from row pass
        c[(size_t)b * RST + NN] = 0.5f / (kd * sr + rd);   // dustbin col
        sums[b] = 0.0f;
    }
}

// ---------------- v = log(c) ----------------
__global__ void vlog_k(const float* __restrict__ c, float* __restrict__ v) {
    int i = blockIdx.x * 256 + threadIdx.x;
    int b = i >> 12, n = i & 4095;
    v[i] = logf(c[(size_t)b * RST + n]);
}

// ---------------- posterior: mass/entropy/top-8 from fp32 sim ----------------
__global__ __launch_bounds__(256) void posterior_k(const float* __restrict__ sim, const float* __restrict__ r,
                                                   const float* __restrict__ v, const float* __restrict__ scal,
                                                   float* __restrict__ ent_out, int* __restrict__ tk_idx,
                                                   float* __restrict__ tk_logp) {
    __shared__ float vs[NN];
    int b = blockIdx.y;
    int t = threadIdx.x;
#pragma unroll
    for (int q = 0; q < 16; q++) vs[t + 256 * q] = v[(size_t)b * NN + t + 256 * q];
    __syncthreads();
    float ict = scal[0];
    int warp = t >> 6, lane = t & 63;
    int wv = blockIdx.x * 4 + warp;
    for (int j = 0; j < 4; j++) {
        int m = wv + 1024 * j;
        const float* Srow = sim + ((size_t)b * NN + m) * NN;
        float u = logf(r[(size_t)b * RST + m]);
        float mass = 0.0f, pl = 0.0f;
        float tv[8]; int ti[8];
#pragma unroll
        for (int k = 0; k < 8; k++) { tv[k] = -3.4e38f; ti[k] = 0x7fffffff; }
#pragma unroll 4
        for (int q = 0; q < 64; q++) {
            int n = lane + 64 * q;
            float s = Srow[n] * ict;
            s = fminf(fmaxf(s, -50.0f), 50.0f);
            float tt = s + vs[n];
            float l = tt + u;
            float lc = fminf(fmaxf(l, -50.0f), 0.0f);
            float p = __expf(lc);
            mass += p;
            pl = fmaf(p, lc, pl);
            if (tt > tv[7]) {                      // lane-local sorted top-8 (stable by index)
                tv[7] = tt; ti[7] = n;
#pragma unroll
                for (int k = 7; k > 0; k--) {
                    if (tv[k] > tv[k - 1]) {
                        float tmv = tv[k]; tv[k] = tv[k - 1]; tv[k - 1] = tmv;
                        int tmi = ti[k]; ti[k] = ti[k - 1]; ti[k - 1] = tmi;
                    }
                }
            }
        }
#pragma unroll
        for (int off = 32; off; off >>= 1) {
            mass += __shfl_down(mass, off);
            pl += __shfl_down(pl, off);
        }
        float outv[8]; int outi[8];
#pragma unroll
        for (int k = 0; k < 8; k++) {              // wave merge: max value, ties -> lower index
            float bv = tv[0]; int bi = ti[0];
#pragma unroll
            for (int off = 32; off; off >>= 1) {
                float ov = __shfl_down(bv, off); int oi = __shfl_down(bi, off);
                if (ov > bv || (ov == bv && oi < bi)) { bv = ov; bi = oi; }
            }
            bv = __shfl(bv, 0); bi = __shfl(bi, 0);
            outv[k] = bv; outi[k] = bi;
            if (ti[0] == bi) {                     // pop from the winning lane
#pragma unroll
                for (int k2 = 0; k2 < 7; k2++) { tv[k2] = tv[k2 + 1]; ti[k2] = ti[k2 + 1]; }
                tv[7] = -3.4e38f; ti[7] = 0x7fffffff;
            }
        }
        if (lane == 0) {
            float rm = fmaxf(mass, 1e-8f);
            float ent = (logf(rm) * mass - pl) / rm;
            float valid = fminf(fmaxf(rm * 8192.0f, 0.0f), 1.0f);
            ent_out[(size_t)b * NN + m] = ent * valid;
            size_t base = ((size_t)b * NN + m) * 8;
#pragma unroll
            for (int k = 0; k < 8; k++) { tk_idx[base + k] = outi[k]; tk_logp[base + k] = outv[k] + u; }
        }
    }
}

// ---------------- geometric consistency ----------------
__global__ __launch_bounds__(256) void geo_k(const int* __restrict__ tk_idx, const float* __restrict__ posA,
                                             const float* __restrict__ posB, float* __restrict__ geo_out) {
    __shared__ float dx[NN], dy[NN];
    int k = blockIdx.x, b = blockIdx.y;
    int t = threadIdx.x;
    const float2* pA = (const float2*)posA + (size_t)b * NN;
    const float2* pB = (const float2*)posB + (size_t)b * NN;
    for (int q = 0; q < 16; q++) {
        int n = t + 256 * q;
        int idx = tk_idx[((size_t)(b * NN + n)) * 8 + k];
        float2 pb = pB[idx];
        float2 pa = pA[n];
        dx[n] = pb.x - pa.x;
        dy[n] = pb.y - pa.y;
    }
    __syncthreads();
    for (int q = 0; q < 16; q++) {
        int n = t + 256 * q;
        int y = n >> 6, x = n & 63;
        int y0 = max(y - 3, 0), y1 = min(y + 3, 63);
        int x0 = max(x - 3, 0), x1 = min(x + 3, 63);
        float sx = 0, sxx = 0, sy = 0, syy = 0;
        for (int yy = y0; yy <= y1; yy++)
            for (int xx = x0; xx <= x1; xx++) {
                float a = dx[(yy << 6) + xx], c2 = dy[(yy << 6) + xx];
                sx += a; sxx = fmaf(a, a, sxx);
                sy += c2; syy = fmaf(c2, c2, syy);
            }
        float inv = 1.0f / (float)((y1 - y0 + 1) * (x1 - x0 + 1));
        float mx = sx * inv, my = sy * inv;
        float vx = fmaxf(sxx * inv - mx * mx, 0.0f);
        float vy = fmaxf(syy * inv - my * my, 0.0f);
        geo_out[((size_t)(b * NN + n)) * 8 + k] = 1.0f / (1.0f + (vx + vy) * 100.0f);
    }
}

// ---------------- refine: softmax-weighted positions ----------------
__global__ __launch_bounds__(256) void refine_k(const float* __restrict__ tk_logp, const int* __restrict__ tk_idx,
                                                const float* __restrict__ geo, const float* __restrict__ posB,
                                                const float* __restrict__ scal, float* __restrict__ refined) {
    int i = blockIdx.x * 256 + threadIdx.x;    // 0..16383
    int b = i >> 12;
    float gw = scal[2];
    const float* lp = tk_logp + (size_t)i * 8;
    const float* gs = geo + (size_t)i * 8;
    const int* ix = tk_idx + (size_t)i * 8;
    const float2* pB = (const float2*)posB + (size_t)b * NN;
    float cb[8]; float mx = -3.4e38f;
#pragma unroll
    for (int k = 0; k < 8; k++) { cb[k] = fmaf(gw, gs[k], lp[k]); mx = fmaxf(mx, cb[k]); }
    float sum = 0.0f, px = 0.0f, py = 0.0f;
#pragma unroll
    for (int k = 0; k < 8; k++) {
        float w = __expf(cb[k] - mx);
        float2 p = pB[ix[k]];
        sum += w; px = fmaf(w, p.x, px); py = fmaf(w, p.y, py);
    }
    float inv = 1.0f / sum;
    px = fminf(fmaxf(px * inv, -1.5f), 1.5f);
    py = fminf(fmaxf(py * inv, -1.5f), 1.5f);
    ((float2*)refined)[i] = make_float2(px, py);
}

extern "C" void kernel_launch(void* const* d_in, const int* in_sizes, int n_in,
                              void* d_out, int out_size, void* d_ws, size_t ws_size,
                              hipStream_t stream) {
    (void)in_sizes; (void)n_in; (void)out_size; (void)ws_size;
    const float* feat_A = (const float*)d_in[0];
    const float* feat_B = (const float*)d_in[1];
    const float* pos_A = (const float*)d_in[2];
    const float* pos_B = (const float*)d_in[3];
    const float* dsc = (const float*)d_in[4];
    const float* gwp = (const float*)d_in[5];
    const float* ctp = (const float*)d_in[6];

    float* out = (float*)d_out;
    float* out_refined = out;                       // [4,4096,2]
    float* out_entropy = out + 32768;               // [4,4096]
    float* out_sim = out + 49152;                   // [4,4096,4096]
    float* out_geo = out + 49152 + (size_t)NB * NN * NN;  // [4,4096,8]

    char* ws = (char*)d_ws;
    size_t off = 0;
    float* scal = (float*)(ws + off); off += 256;
    float* invA = (float*)(ws + off); off += (size_t)NB * NN * 4;
    float* invB = (float*)(ws + off); off += (size_t)NB * NN * 4;
    float* rr = (float*)(ws + off); off += (size_t)NB * RST * 4 + 64;
    float* cc = (float*)(ws + off); off += (size_t)NB * RST * 4 + 64;
    float* vv = (float*)(ws + off); off += (size_t)NB * NN * 4;
    float* sums = (float*)(ws + off); off += 256;
    float* partial = (float*)(ws + off); off += (size_t)NB * 64 * NN * 4;
    int* tki = (int*)(ws + off); off += (size_t)NB * NN * 8 * 4;
    float* tkl = (float*)(ws + off); off += (size_t)NB * NN * 8 * 4;

    scalars_k<<<1, 64, 0, stream>>>(dsc, gwp, ctp, scal);
    invnorm_k<<<8192, 256, 0, stream>>>(feat_A, feat_B, invA, invB);
    gemm_k<<<dim3(32, 32, NB), 256, 0, stream>>>(feat_A, feat_B, invA, invB, out_sim);
    init_sink_k<<<(NB * RST + 255) / 256, 256, 0, stream>>>(cc, sums);
    for (int it = 0; it < 15; it++) {
        row_pass_k<<<dim3(256, NB), 256, 0, stream>>>(out_sim, cc, rr, sums, scal);
        col_partial_k<<<dim3(2, 64, NB), 256, 0, stream>>>(out_sim, rr, partial, scal);
        col_finalize_k<<<dim3(16, NB), 256, 0, stream>>>(partial, rr, cc, sums, scal);
    }
    vlog_k<<<64, 256, 0, stream>>>(cc, vv);
    posterior_k<<<dim3(256, NB), 256, 0, stream>>>(out_sim, rr, vv, scal, out_entropy, tki, tkl);
    geo_k<<<dim3(8, NB), 256, 0, stream>>>(tki, pos_A, pos_B, out_geo);
    refine_k<<<64, 256, 0, stream>>>(tkl, tki, out_geo, pos_B, scal, out_refined);
}